// Round 1
// baseline (806.255 us; speedup 1.0000x reference)
//
#include <hip/hip_runtime.h>
#include <hip/hip_bf16.h>

// TT-matrix embedding: vocab 50*60*60, embed 8*8*8, rank 16.
// One 64-lane wave per token; lane l=(a*8+b) computes emb[a,b,0:8].
// Token order u = sent*64 + batch matches both x's row-major layout and the
// output layout (the reference's two transposes cancel).

#define M2M3 3600u
#define M3 60u

__global__ __launch_bounds__(256) void tt_embed_kernel(
    const int* __restrict__ x,          // [T] token ids (row-major [sent,batch])
    const float* __restrict__ c1,       // [50][8][16]
    const float* __restrict__ c2,       // [60][16][8][16]
    const float* __restrict__ c3,       // [60][16][8]
    float* __restrict__ out,            // [T][512]
    int T)
{
    const int u    = (int)((blockIdx.x * blockDim.x + threadIdx.x) >> 6); // token
    const int lane = threadIdx.x & 63;
    if (u >= T) return;

    const int a = lane >> 3;   // n1 index
    const int b = lane & 7;    // n2 index

    const unsigned id  = (unsigned)x[u];
    const unsigned i1  = id / M2M3;
    const unsigned rem = id - i1 * M2M3;
    const unsigned i2  = rem / M3;
    const unsigned i3  = rem - i2 * M3;

    const float4* __restrict__ g1 = (const float4*)(c1 + i1 * 128u + a * 16);   // g1[a][r], r=0..15
    const float*  __restrict__ g2 = c2 + i2 * 2048u + b * 16;                   // g2[r][b][s]
    const float4* __restrict__ g3 = (const float4*)(c3 + i3 * 128u);            // g3[s][c]

    // load this lane's g1 row (16 contiguous floats)
    float4 a1v[4];
#pragma unroll
    for (int q = 0; q < 4; ++q) a1v[q] = g1[q];
    const float* a1f = (const float*)a1v;

    // t12[s] = sum_r g1[a][r] * g2[r][b][s]
    float t12[16];
#pragma unroll
    for (int s = 0; s < 16; ++s) t12[s] = 0.f;

#pragma unroll
    for (int r = 0; r < 16; ++r) {
        const float a1 = a1f[r];
        const float4* row = (const float4*)(g2 + r * 128);
#pragma unroll
        for (int q = 0; q < 4; ++q) {
            const float4 v = row[q];
            t12[q * 4 + 0] = fmaf(a1, v.x, t12[q * 4 + 0]);
            t12[q * 4 + 1] = fmaf(a1, v.y, t12[q * 4 + 1]);
            t12[q * 4 + 2] = fmaf(a1, v.z, t12[q * 4 + 2]);
            t12[q * 4 + 3] = fmaf(a1, v.w, t12[q * 4 + 3]);
        }
    }

    // o[c] = sum_s t12[s] * g3[s][c]
    float o[8];
#pragma unroll
    for (int c = 0; c < 8; ++c) o[c] = 0.f;

#pragma unroll
    for (int s = 0; s < 16; ++s) {
        const float ts = t12[s];
        const float4 w0 = g3[s * 2 + 0];
        const float4 w1 = g3[s * 2 + 1];
        o[0] = fmaf(ts, w0.x, o[0]);
        o[1] = fmaf(ts, w0.y, o[1]);
        o[2] = fmaf(ts, w0.z, o[2]);
        o[3] = fmaf(ts, w0.w, o[3]);
        o[4] = fmaf(ts, w1.x, o[4]);
        o[5] = fmaf(ts, w1.y, o[5]);
        o[6] = fmaf(ts, w1.z, o[6]);
        o[7] = fmaf(ts, w1.w, o[7]);
    }

    // store: lane l writes out[u*512 + l*8 .. +8) — wave covers 2 KiB contiguous
    float4* dst = (float4*)(out + (size_t)u * 512 + lane * 8);
    dst[0] = make_float4(o[0], o[1], o[2], o[3]);
    dst[1] = make_float4(o[4], o[5], o[6], o[7]);
}

extern "C" void kernel_launch(void* const* d_in, const int* in_sizes, int n_in,
                              void* d_out, int out_size, void* d_ws, size_t ws_size,
                              hipStream_t stream) {
    const int*   x  = (const int*)d_in[0];
    const float* c1 = (const float*)d_in[1];
    const float* c2 = (const float*)d_in[2];
    const float* c3 = (const float*)d_in[3];
    float* out = (float*)d_out;

    const int T = in_sizes[0];              // 131072 tokens
    const int waves_per_block = 4;          // 256 threads
    const int blocks = (T + waves_per_block - 1) / waves_per_block;

    tt_embed_kernel<<<blocks, 256, 0, stream>>>(x, c1, c2, c3, out, T);
}

// Round 2
// 335.770 us; speedup vs baseline: 2.4012x; 2.4012x over previous
//
#include <hip/hip_runtime.h>
#include <hip/hip_bf16.h>

// TT-matrix embedding: vocab 50*60*60, embed 8*8*8, rank 16.
//
// Two-phase scheme:
//   Phase 1: t12tab[i1*60+i2] = g1[i1] @ g2[i2]  (3000 pairs x 1024 floats = 12.3 MB in d_ws)
//            stored s-major: tab[pair*1024 + q*256 + ab*4 + j]  (s = 4q+j, ab = a*8+b)
//            so phase-2 lane `ab` reads its 16 values with 4 fully-coalesced float4 loads.
//   Phase 2: one wave per token; lane ab computes emb[a,b,0:8] = sum_s t12[ab,s] * g3[i3][s,0:8].
//            Token id is made wave-uniform via readfirstlane -> i1/i2/i3 scalar, g3 loads go
//            through the scalar/constant path (c3 is only 30 KB, cache-resident).
//
// Round-1 post-mortem: single-pass kernel was latency-bound (VALUBusy 12.8%, HBM 5.4%):
// ~100 dependent vector loads/lane thrashing L1. This cuts vector loads/lane to 5.

#define M2M3 3600u
#define M3 60u

__global__ __launch_bounds__(256) void tt_pair_kernel(
    const float* __restrict__ c1,   // [50][8][16]
    const float* __restrict__ c2,   // [60][16][8][16]
    float* __restrict__ tab)        // [3000][1024]
{
    const int pair = blockIdx.x;            // i1*60 + i2
    const int i1 = pair / 60;
    const int i2 = pair - i1 * 60;
    const int tid = threadIdx.x;
    const int q  = tid >> 6;                // s-quad 0..3
    const int ab = tid & 63;
    const int a  = ab >> 3;
    const int b  = ab & 7;

    const float* __restrict__ g1 = c1 + i1 * 128 + a * 16;            // g1[a][r]
    const float* __restrict__ g2 = c2 + i2 * 2048 + b * 16 + q * 4;   // g2[r][b][4q..]

    float4 acc = make_float4(0.f, 0.f, 0.f, 0.f);
#pragma unroll
    for (int r = 0; r < 16; ++r) {
        const float a1 = g1[r];
        const float4 v = *(const float4*)(g2 + r * 128);
        acc.x = fmaf(a1, v.x, acc.x);
        acc.y = fmaf(a1, v.y, acc.y);
        acc.z = fmaf(a1, v.z, acc.z);
        acc.w = fmaf(a1, v.w, acc.w);
    }
    // layout: pair*1024 + q*256 + ab*4  ==  pair*1024 + tid*4  (contiguous per block)
    *(float4*)(tab + (size_t)pair * 1024 + tid * 4) = acc;
}

__global__ __launch_bounds__(256) void tt_embed2_kernel(
    const int* __restrict__ x,      // [T]
    const float* __restrict__ c3,   // [60][16][8]
    const float* __restrict__ tab,  // [3000][1024]
    float* __restrict__ out,        // [T][512]
    int T)
{
    const int u    = (int)((blockIdx.x * blockDim.x + threadIdx.x) >> 6);
    const int lane = threadIdx.x & 63;
    if (u >= T) return;

    // token id is identical across the wave's 64 lanes -> make it scalar
    const unsigned id  = __builtin_amdgcn_readfirstlane((unsigned)x[u]);
    const unsigned i1  = id / M2M3;
    const unsigned rem = id - i1 * M2M3;
    const unsigned i2  = rem / M3;
    const unsigned i3  = rem - i2 * M3;

    // 4 coalesced float4 loads: instruction q reads 1 KiB contiguous across the wave
    const float* tp = tab + (size_t)(i1 * 60u + i2) * 1024u;
    float4 t[4];
#pragma unroll
    for (int q = 0; q < 4; ++q)
        t[q] = *(const float4*)(tp + q * 256 + lane * 4);
    const float* tf = (const float*)t;      // tf[s], s = 0..15

    // g3 slice: wave-uniform scalar base -> constant-cache loads (30 KB table, hot)
    const float4* __restrict__ g3 = (const float4*)(c3 + i3 * 128u);   // g3[s][c]

    float o[8];
#pragma unroll
    for (int c = 0; c < 8; ++c) o[c] = 0.f;

#pragma unroll
    for (int s = 0; s < 16; ++s) {
        const float ts = tf[s];
        const float4 w0 = g3[s * 2 + 0];
        const float4 w1 = g3[s * 2 + 1];
        o[0] = fmaf(ts, w0.x, o[0]);
        o[1] = fmaf(ts, w0.y, o[1]);
        o[2] = fmaf(ts, w0.z, o[2]);
        o[3] = fmaf(ts, w0.w, o[3]);
        o[4] = fmaf(ts, w1.x, o[4]);
        o[5] = fmaf(ts, w1.y, o[5]);
        o[6] = fmaf(ts, w1.z, o[6]);
        o[7] = fmaf(ts, w1.w, o[7]);
    }

    float4* dst = (float4*)(out + (size_t)u * 512 + lane * 8);
    dst[0] = make_float4(o[0], o[1], o[2], o[3]);
    dst[1] = make_float4(o[4], o[5], o[6], o[7]);
}

// ---- fallback (round-1 single-pass kernel) if d_ws is too small ----
__global__ __launch_bounds__(256) void tt_embed_kernel(
    const int* __restrict__ x, const float* __restrict__ c1,
    const float* __restrict__ c2, const float* __restrict__ c3,
    float* __restrict__ out, int T)
{
    const int u    = (int)((blockIdx.x * blockDim.x + threadIdx.x) >> 6);
    const int lane = threadIdx.x & 63;
    if (u >= T) return;
    const int a = lane >> 3, b = lane & 7;
    const unsigned id  = (unsigned)x[u];
    const unsigned i1  = id / M2M3;
    const unsigned rem = id - i1 * M2M3;
    const unsigned i2  = rem / M3;
    const unsigned i3  = rem - i2 * M3;
    const float4* g1 = (const float4*)(c1 + i1 * 128u + a * 16);
    const float*  g2 = c2 + i2 * 2048u + b * 16;
    const float4* g3 = (const float4*)(c3 + i3 * 128u);
    float4 a1v[4];
#pragma unroll
    for (int q = 0; q < 4; ++q) a1v[q] = g1[q];
    const float* a1f = (const float*)a1v;
    float t12[16];
#pragma unroll
    for (int s = 0; s < 16; ++s) t12[s] = 0.f;
#pragma unroll
    for (int r = 0; r < 16; ++r) {
        const float a1 = a1f[r];
        const float4* row = (const float4*)(g2 + r * 128);
#pragma unroll
        for (int q = 0; q < 4; ++q) {
            const float4 v = row[q];
            t12[q*4+0] = fmaf(a1, v.x, t12[q*4+0]);
            t12[q*4+1] = fmaf(a1, v.y, t12[q*4+1]);
            t12[q*4+2] = fmaf(a1, v.z, t12[q*4+2]);
            t12[q*4+3] = fmaf(a1, v.w, t12[q*4+3]);
        }
    }
    float o[8];
#pragma unroll
    for (int c = 0; c < 8; ++c) o[c] = 0.f;
#pragma unroll
    for (int s = 0; s < 16; ++s) {
        const float ts = t12[s];
        const float4 w0 = g3[s*2+0];
        const float4 w1 = g3[s*2+1];
        o[0]=fmaf(ts,w0.x,o[0]); o[1]=fmaf(ts,w0.y,o[1]);
        o[2]=fmaf(ts,w0.z,o[2]); o[3]=fmaf(ts,w0.w,o[3]);
        o[4]=fmaf(ts,w1.x,o[4]); o[5]=fmaf(ts,w1.y,o[5]);
        o[6]=fmaf(ts,w1.z,o[6]); o[7]=fmaf(ts,w1.w,o[7]);
    }
    float4* dst = (float4*)(out + (size_t)u * 512 + lane * 8);
    dst[0] = make_float4(o[0], o[1], o[2], o[3]);
    dst[1] = make_float4(o[4], o[5], o[6], o[7]);
}

extern "C" void kernel_launch(void* const* d_in, const int* in_sizes, int n_in,
                              void* d_out, int out_size, void* d_ws, size_t ws_size,
                              hipStream_t stream) {
    const int*   x  = (const int*)d_in[0];
    const float* c1 = (const float*)d_in[1];
    const float* c2 = (const float*)d_in[2];
    const float* c3 = (const float*)d_in[3];
    float* out = (float*)d_out;

    const int T = in_sizes[0];                       // 131072 tokens
    const size_t tab_bytes = 3000u * 1024u * sizeof(float);  // 12.3 MB

    if (ws_size >= tab_bytes) {
        float* tab = (float*)d_ws;
        tt_pair_kernel<<<3000, 256, 0, stream>>>(c1, c2, tab);
        const int blocks = (T + 3) / 4;              // 4 waves (tokens) per block
        tt_embed2_kernel<<<blocks, 256, 0, stream>>>(x, c3, tab, out, T);
    } else {
        const int blocks = (T + 3) / 4;
        tt_embed_kernel<<<blocks, 256, 0, stream>>>(x, c1, c2, c3, out, T);
    }
}